// Round 1
// baseline (815.662 us; speedup 1.0000x reference)
//
#include <hip/hip_runtime.h>
#include <cstdint>
#include <cstddef>

// MultiScaleQuantizer: z (256,32,16,16) fp32, embed (4096,32) fp32.
// Outputs concat (all read back as fp32): f_hat (2097152), idx@pn=1 (256),
// idx@2 (1024), idx@4 (4096), idx@8 (16384), idx@16 (65536), loss (1).
// Total 2184449 floats.

#define B_   256
#define C_   32
#define V_   4096
#define NTOT 2097152   // 256*32*16*16

// ---------------- prep: embed transpose + ||e||^2 ----------------
__global__ __launch_bounds__(256) void prep_embed_kernel(
    const float* __restrict__ embed, float* __restrict__ embedT,
    float* __restrict__ se)
{
  int v = blockIdx.x * 256 + threadIdx.x;
  if (v >= V_) return;
  float s = 0.f;
#pragma unroll
  for (int c = 0; c < 32; ++c) {
    float e = embed[(size_t)v * 32 + c];
    embedT[(size_t)c * V_ + v] = e;
    s += e * e;                       // (embed*embed).sum(-1), sequential
  }
  se[v] = s;
}

// ---------------- init: f_rest = z, f_hat(out) = 0 ----------------
__global__ __launch_bounds__(256) void init_kernel(
    const float* __restrict__ z, float* __restrict__ f_rest,
    float* __restrict__ f_hat)
{
  int t = blockIdx.x * 256 + threadIdx.x;
  f_rest[t] = z[t];
  f_hat[t] = 0.f;
}

// ---------------- bicubic weight tables + zero loss accumulators ----------
// tbl layout: [pn_i in {1,2,4,8}][16 output rows][8 cols max]
__global__ void tables_kernel(float* __restrict__ tbl, float* __restrict__ losses)
{
  int tid = threadIdx.x;
  if (tid < 8) losses[tid] = 0.f;
  if (tid >= 64) return;
  int pn_i = tid >> 4;          // 0..3 -> pn = 1,2,4,8
  int o    = tid & 15;          // output row
  int pn   = 1 << pn_i;
  double scale = (double)pn / 16.0;
  double x  = (o + 0.5) * scale - 0.5;
  double x0 = floor(x);
  double tf = x - x0;
  float row[8];
#pragma unroll
  for (int h = 0; h < 8; ++h) row[h] = 0.f;
  const double A = -0.75;
#pragma unroll
  for (int off = -1; off <= 2; ++off) {
    double s = fabs(tf - (double)off);
    double cub;
    if (s <= 1.0)      cub = ((A + 2.0) * s - (A + 3.0)) * s * s + 1.0;
    else if (s < 2.0)  cub = (((s - 5.0) * s + 8.0) * s - 4.0) * A;
    else               cub = 0.0;
    int idx = (int)x0 + off;
    idx = min(max(idx, 0), pn - 1);
    // numpy: float32 array += float64 scalar (upcast, add, downcast)
    row[idx] = (float)((double)row[idx] + cub);
  }
#pragma unroll
  for (int h = 0; h < 8; ++h) tbl[pn_i * 128 + o * 8 + h] = row[h];
}

// ---------------- area downsample + pack to (N,32) ----------------
// n = b*pn*pn + ph*pn + pw ; zpack[n*32+c]
__global__ __launch_bounds__(256) void down_pack_kernel(
    const float* __restrict__ f_rest, float* __restrict__ zpack, int pn)
{
  int t = blockIdx.x * 256 + threadIdx.x;
  int c = t & 31;
  int n = t >> 5;
  int pn2 = pn * pn;
  int pw = n % pn;
  int ph = (n / pn) % pn;
  int b  = n / pn2;
  int k  = 16 / pn;
  const float* src = f_rest + (size_t)(b * 32 + c) * 256;
  float s = 0.f;
  for (int i = 0; i < k; ++i)
    for (int j = 0; j < k; ++j)
      s += src[(ph * k + i) * 16 + (pw * k + j)];
  zpack[(size_t)n * 32 + c] = s * (1.0f / (k * k));   // 1/k^2 is pow2: exact
}

// ---------------- ||z||^2 per point ----------------
__global__ __launch_bounds__(256) void sz_kernel(
    const float* __restrict__ zpack, float* __restrict__ szb, int N)
{
  int n = blockIdx.x * 256 + threadIdx.x;
  if (n >= N) return;
  const float* zp = zpack + (size_t)n * 32;
  float s = 0.f;
#pragma unroll
  for (int c = 0; c < 32; ++c) s += zp[c] * zp[c];
  szb[n] = s;
}

// ---------------- fused distance + argmin ----------------
// Block: 256 threads = 16(tp) x 16(tv); 64 points x 64 codes per chunk,
// 4x4 register blocking. blockIdx.x: point block (64 pts);
// blockIdx.y: codebook chunk of `vchunk` codes.
__global__ __launch_bounds__(256) void vq_argmin_kernel(
    const float* __restrict__ zpack, const float* __restrict__ szb,
    const float* __restrict__ embedT, const float* __restrict__ se,
    float2* __restrict__ partials, int vchunk, int nvch)
{
  __shared__ __align__(16) float zT[32 * 64];
  __shared__ __align__(16) float eT[32 * 64];
  __shared__ float2 red[64 * 16];
  const int tid = threadIdx.x;
  const int n0  = blockIdx.x * 64;
  const int v0  = blockIdx.y * vchunk;

  // stage zT[k][n] (transpose of zpack rows)
  {
    int nl = tid >> 3, c4 = tid & 7;
#pragma unroll
    for (int h2 = 0; h2 < 2; ++h2) {
      int n = nl + h2 * 32;
      float4 zv = *(const float4*)(zpack + (size_t)(n0 + n) * 32 + c4 * 4);
      zT[(c4 * 4 + 0) * 64 + n] = zv.x;
      zT[(c4 * 4 + 1) * 64 + n] = zv.y;
      zT[(c4 * 4 + 2) * 64 + n] = zv.z;
      zT[(c4 * 4 + 3) * 64 + n] = zv.w;
    }
  }
  const int tp = tid & 15, tv = tid >> 4;
  float sz4[4];
#pragma unroll
  for (int i = 0; i < 4; ++i) sz4[i] = szb[n0 + tp * 4 + i];
  float mind[4]; int mini[4];
#pragma unroll
  for (int i = 0; i < 4; ++i) { mind[i] = 3.4e38f; mini[i] = 0x7fffffff; }

  for (int cc = 0; cc < vchunk; cc += 64) {
    __syncthreads();   // covers zT staging on first iter, eT reuse after
    {
      int k = tid >> 4, j4 = tid & 15;
      *(float4*)(eT + k * 64 + j4 * 4) =
          *(const float4*)(embedT + (size_t)k * V_ + (v0 + cc) + j4 * 4);
      *(float4*)(eT + (k + 16) * 64 + j4 * 4) =
          *(const float4*)(embedT + (size_t)(k + 16) * V_ + (v0 + cc) + j4 * 4);
    }
    __syncthreads();
    float acc[4][4] = {{0,0,0,0},{0,0,0,0},{0,0,0,0},{0,0,0,0}};
#pragma unroll
    for (int k = 0; k < 32; ++k) {
      float4 z4 = *(const float4*)(zT + k * 64 + tp * 4);
      float4 e4 = *(const float4*)(eT + k * 64 + tv * 4);
      float zr[4] = {z4.x, z4.y, z4.z, z4.w};
      float er[4] = {e4.x, e4.y, e4.z, e4.w};
#pragma unroll
      for (int i = 0; i < 4; ++i)
#pragma unroll
        for (int j = 0; j < 4; ++j)
          acc[i][j] = fmaf(zr[i], er[j], acc[i][j]);
    }
#pragma unroll
    for (int j = 0; j < 4; ++j) {
      int v = v0 + cc + tv * 4 + j;
      float sev = se[v];
#pragma unroll
      for (int i = 0; i < 4; ++i) {
        // matches: (sz - 2*dot) + se  (2*acc exact, single rounding on sub)
        float d = fmaf(-2.0f, acc[i][j], sz4[i]) + sev;
        if (d < mind[i]) { mind[i] = d; mini[i] = v; }  // strict <: first idx wins
      }
    }
  }

  __syncthreads();
#pragma unroll
  for (int i = 0; i < 4; ++i)
    red[(tp * 4 + i) * 16 + tv] = make_float2(mind[i], __int_as_float(mini[i]));
  __syncthreads();
  if (tid < 64) {
    float bd = 3.4e38f; int bi = 0x7fffffff;
    for (int t2 = 0; t2 < 16; ++t2) {
      float2 r = red[tid * 16 + t2];
      int v = __float_as_int(r.y);
      if (r.x < bd || (r.x == bd && v < bi)) { bd = r.x; bi = v; }
    }
    partials[(size_t)(n0 + tid) * nvch + blockIdx.y] =
        make_float2(bd, __int_as_float(bi));
  }
}

// ---------------- reduce partial argmins over codebook chunks ----------------
__global__ __launch_bounds__(256) void vq_reduce_kernel(
    const float2* __restrict__ partials, int N, int nvch,
    int* __restrict__ idx_list, float* __restrict__ idx_out_f)
{
  int n = blockIdx.x * 256 + threadIdx.x;
  if (n >= N) return;
  float bd = 3.4e38f; int bi = 0x7fffffff;
  for (int t = 0; t < nvch; ++t) {
    float2 r = partials[(size_t)n * nvch + t];
    int v = __float_as_int(r.y);
    if (r.x < bd || (r.x == bd && v < bi)) { bd = r.x; bi = v; }
  }
  idx_list[n] = bi;
  idx_out_f[n] = (float)bi;          // harness reads idx as fp32
}

// ---------------- loss: sum (embed[idx]-z)^2 ----------------
__global__ __launch_bounds__(256) void loss_kernel(
    const float* __restrict__ zpack, const float* __restrict__ embed,
    const int* __restrict__ idx_list, float* __restrict__ loss_slot, int N)
{
  int t = blockIdx.x * 256 + threadIdx.x;
  float v = 0.f;
  if (t < N * 32) {
    int n = t >> 5, c = t & 31;
    float zq = embed[(size_t)idx_list[n] * 32 + c];
    float d = zq - zpack[t];
    v = d * d;
  }
  __shared__ float sm[256];
  sm[threadIdx.x] = v;
  __syncthreads();
  for (int s = 128; s > 0; s >>= 1) {
    if (threadIdx.x < s) sm[threadIdx.x] += sm[threadIdx.x + s];
    __syncthreads();
  }
  if (threadIdx.x == 0) atomicAdd(loss_slot, sm[0]);
}

// ---------------- bicubic upsample + f_hat += / f_rest -= ----------------
// t = ((b*32+c)*16+o)*16+p
__global__ __launch_bounds__(256) void up_update_kernel(
    const float* __restrict__ embed, const int* __restrict__ idx_list,
    const float* __restrict__ tbl, float* __restrict__ f_hat,
    float* __restrict__ f_rest, int pn)
{
  int t = blockIdx.x * 256 + threadIdx.x;
  int p = t & 15;
  int o = (t >> 4) & 15;
  int c = (t >> 8) & 31;
  int b = t >> 13;
  const float* Wo = tbl + o * 8;
  const float* Wp = tbl + p * 8;
  float acc = 0.f;
  for (int w = 0; w < pn; ++w) {
    float inner = 0.f;                 // reference: h-einsum first, then w
    for (int h = 0; h < pn; ++h) {
      int idx = idx_list[(b * pn + h) * pn + w];
      inner = fmaf(Wo[h], embed[(size_t)idx * 32 + c], inner);
    }
    acc = fmaf(Wp[w], inner, acc);
  }
  f_hat[t] += acc;
  f_rest[t] -= acc;
}

// ---------------- last scale (pn=16): f_hat += embed[idx] ----------------
__global__ __launch_bounds__(256) void final_add_kernel(
    const float* __restrict__ embed, const int* __restrict__ idx_list,
    float* __restrict__ f_hat)
{
  int t = blockIdx.x * 256 + threadIdx.x;
  int s = t & 255;
  int c = (t >> 8) & 31;
  int b = t >> 13;
  int n = b * 256 + s;
  f_hat[t] += embed[(size_t)idx_list[n] * 32 + c];
}

// ---------------- combine loss ----------------
__global__ void loss_final_kernel(const float* __restrict__ losses,
                                  float* __restrict__ out_loss)
{
  if (threadIdx.x != 0) return;
  const float numel[5] = {8192.f, 32768.f, 131072.f, 524288.f, 2097152.f};
  float v = 0.f;
  for (int i = 0; i < 5; ++i) {
    float m = losses[i] / numel[i];
    float li = 0.25f * m + m;          // beta*mean + mean
    v = v + li;
  }
  out_loss[0] = v / 5.f;
}

// =========================== host launcher ===========================
extern "C" void kernel_launch(void* const* d_in, const int* in_sizes, int n_in,
                              void* d_out, int out_size, void* d_ws, size_t ws_size,
                              hipStream_t stream)
{
  const float* z     = (const float*)d_in[0];
  const float* embed = (const float*)d_in[1];
  float* out = (float*)d_out;
  float* ws  = (float*)d_ws;

  // ws layout (floats)
  float*  f_rest   = ws;                       // 2097152
  float*  zpack    = ws + 2097152;             // 2097152
  float*  embedT   = ws + 4194304;             // 131072
  float*  se       = ws + 4325376;             // 4096
  float*  szbuf    = ws + 4329472;             // 65536
  float2* partials = (float2*)(ws + 4395008);  // 65536 float2 = 131072 floats
  int*    idx_list = (int*)(ws + 4526080);     // 65536 ints
  float*  losses   = ws + 4591616;             // 8
  float*  tables   = ws + 4591624;             // 512

  prep_embed_kernel<<<V_ / 256, 256, 0, stream>>>(embed, embedT, se);
  init_kernel<<<NTOT / 256, 256, 0, stream>>>(z, f_rest, out);
  tables_kernel<<<1, 64, 0, stream>>>(tables, losses);

  const int PN[5] = {1, 2, 4, 8, 16};
  const int NV[5] = {32, 16, 8, 2, 1};   // codebook splits (keep >=128 blocks)
  int idx_off = NTOT;
  for (int i = 0; i < 5; ++i) {
    int pn = PN[i];
    int N  = B_ * pn * pn;
    int nvch = NV[i];
    int vchunk = V_ / nvch;
    down_pack_kernel<<<(N * 32) / 256, 256, 0, stream>>>(f_rest, zpack, pn);
    sz_kernel<<<(N + 255) / 256, 256, 0, stream>>>(zpack, szbuf, N);
    dim3 gA(N / 64, nvch);
    vq_argmin_kernel<<<gA, 256, 0, stream>>>(zpack, szbuf, embedT, se,
                                             partials, vchunk, nvch);
    vq_reduce_kernel<<<(N + 255) / 256, 256, 0, stream>>>(
        partials, N, nvch, idx_list, out + idx_off);
    loss_kernel<<<(N * 32) / 256, 256, 0, stream>>>(zpack, embed, idx_list,
                                                    losses + i, N);
    if (i < 4)
      up_update_kernel<<<NTOT / 256, 256, 0, stream>>>(embed, idx_list,
                                                       tables + i * 128, out,
                                                       f_rest, pn);
    else
      final_add_kernel<<<NTOT / 256, 256, 0, stream>>>(embed, idx_list, out);
    idx_off += N;
  }
  loss_final_kernel<<<1, 1, 0, stream>>>(losses, out + 2184448);
}